// Round 15
// baseline (976.996 us; speedup 1.0000x reference)
//
#include <hip/hip_runtime.h>
#include <hip/hip_fp16.h>
#include <cstddef>

#define NN 50000
#define NE 800000
#define D 128
#define BN_EPS 1e-5f

typedef __attribute__((ext_vector_type(8))) short bf16x8;
typedef __attribute__((ext_vector_type(4))) float f32x4;
typedef __attribute__((ext_vector_type(4))) unsigned short us4;

__device__ __forceinline__ unsigned short f2bf(float x) {
    unsigned u = __float_as_uint(x);
    return (unsigned short)((u + 0x7fffu + ((u >> 16) & 1u)) >> 16);  // RNE
}

// ---------------------------------------------------------------------------
// W prep: W[k][n] f32 -> fragment-linear bf16 Wt (verified R2: B-operand frag)
// ---------------------------------------------------------------------------
__global__ __launch_bounds__(256) void wprep_kernel(
    const float* __restrict__ W, unsigned short* __restrict__ Wt)
{
    const int idx = blockIdx.x * 256 + threadIdx.x;   // [0, 16384)
    const int j  = idx & 7;
    const int l  = (idx >> 3) & 63;
    const int ks = (idx >> 9) & 3;
    const int ct = (idx >> 11) & 7;
    const int n  = 16 * ct + (l & 15);
    const int k  = 32 * ks + ((l >> 4) << 3) + j;
    Wt[idx] = f2bf(W[k * 128 + n]);
}

// ---------------------------------------------------------------------------
// R7-proven MFMA 2-layer MLP (R2 structure: X in swizzled LDS, W frags in
// VGPRs, OUTB f32 transpose buffer, in-kernel OUTB-based BN stats, fp16 x2
// out) with SINGLE-bf16 X/Y (no hi/lo split): halves MFMA + pack VALU, LDS
// 66->50KB -> 3 blocks/CU. Error budget: bf16 X rounding adds ~0.02-0.05
// absmax on top of 0.031 (threshold 0.175).
// MODE 0 (edge): X = e+h[src]+h[dst]. MODE 1 (node): X = h+agg (guarded).
// ---------------------------------------------------------------------------
template<int MODE, int HALFX>
__global__ __launch_bounds__(256, 3) void mlp_mfma_kernel(
    const float* __restrict__ h, const float* __restrict__ e_or_agg,
    const int* __restrict__ src, const int* __restrict__ dst,
    const unsigned short* __restrict__ Wt1, const float* __restrict__ b1,
    const unsigned short* __restrict__ Wt2, const float* __restrict__ b2,
    void* __restrict__ x2out_v, float* __restrict__ stats)
{
    __shared__ __align__(16) unsigned short Xh[8192];   // 64 x 128 bf16 (swizzled)
    __shared__ __align__(16) float OUTB[64 * 132];      // f32 transpose buffer

    const int tid  = threadIdx.x;
    const int lane = tid & 63;
    const int w    = tid >> 6;        // wave id 0..3 -> rows 16w..16w+15
    const int cg   = tid & 31;
    const int rg   = tid >> 5;
    const int c0   = cg * 4;
    const long r0  = (long)blockIdx.x * 64;

    // ---- W1 fragments -> VGPRs ----
    const bf16x8* Wg1 = (const bf16x8*)Wt1;
    bf16x8 wf[8][4];
#pragma unroll
    for (int ct = 0; ct < 8; ++ct)
#pragma unroll
        for (int ks = 0; ks < 4; ++ks)
            wf[ct][ks] = Wg1[(ct * 4 + ks) * 64 + lane];

    // ---- stage X as single bf16 into swizzled LDS ----
#pragma unroll
    for (int p = 0; p < 8; ++p) {
        const int  row  = p * 8 + rg;
        const long grow = r0 + row;
        float4 v = make_float4(0.f, 0.f, 0.f, 0.f);
        if (MODE == 0) {
            const int sN = src[grow];
            const int dN = dst[grow];
            const float4 ev = *(const float4*)(e_or_agg + (size_t)grow * D + c0);
            const float4 hs = *(const float4*)(h + (size_t)sN * D + c0);
            const float4 hd = *(const float4*)(h + (size_t)dN * D + c0);
            v.x = ev.x + hs.x + hd.x; v.y = ev.y + hs.y + hd.y;
            v.z = ev.z + hs.z + hd.z; v.w = ev.w + hs.w + hd.w;
        } else {
            if (grow < NN) {
                const float4 hv = *(const float4*)(h + (size_t)grow * D + c0);
                const float4 av = *(const float4*)(e_or_agg + (size_t)grow * D + c0);
                v.x = hv.x + av.x; v.y = hv.y + av.y;
                v.z = hv.z + av.z; v.w = hv.w + av.w;
            }
        }
        us4 hi;
        hi.x = f2bf(v.x); hi.y = f2bf(v.y);
        hi.z = f2bf(v.z); hi.w = f2bf(v.w);
        const int addr = row * 128 + (((c0 >> 3) ^ (row & 7)) << 3) + (c0 & 7);
        *(us4*)&Xh[addr] = hi;
    }
    __syncthreads();

    // ---- GEMM1 ----
    const int arow = 16 * w + (lane & 15);
    bf16x8 ah[4];
#pragma unroll
    for (int ks = 0; ks < 4; ++ks) {
        const int col0  = 32 * ks + ((lane >> 4) << 3);
        const int aaddr = arow * 128 + (((col0 >> 3) ^ (arow & 7)) << 3);
        ah[ks] = *(const bf16x8*)&Xh[aaddr];
    }
    f32x4 acc[8];
#pragma unroll
    for (int ct = 0; ct < 8; ++ct) acc[ct] = (f32x4){0.f, 0.f, 0.f, 0.f};
#pragma unroll
    for (int ct = 0; ct < 8; ++ct)
#pragma unroll
        for (int ks = 0; ks < 4; ++ks)
            acc[ct] = __builtin_amdgcn_mfma_f32_16x16x32_bf16(ah[ks], wf[ct][ks], acc[ct], 0, 0, 0);

    // ---- issue W2 loads (overwrite wf) ----
    const bf16x8* Wg2 = (const bf16x8*)Wt2;
#pragma unroll
    for (int ct = 0; ct < 8; ++ct)
#pragma unroll
        for (int ks = 0; ks < 4; ++ks)
            wf[ct][ks] = Wg2[(ct * 4 + ks) * 64 + lane];

    // ---- epilogue1: bias + relu -> f32 transpose buffer ----
#pragma unroll
    for (int ct = 0; ct < 8; ++ct) {
        const float b1c = b1[16 * ct + (lane & 15)];
#pragma unroll
        for (int r = 0; r < 4; ++r) {
            const int row = 16 * w + ((lane >> 4) << 2) + r;
            OUTB[row * 132 + 16 * ct + (lane & 15)] = fmaxf(acc[ct][r] + b1c, 0.f);
        }
    }
    __syncthreads();

    // ---- restage Y as single bf16 ----
#pragma unroll
    for (int p = 0; p < 8; ++p) {
        const int row = p * 8 + rg;
        const float4 v = *(const float4*)&OUTB[row * 132 + c0];
        us4 hi;
        hi.x = f2bf(v.x); hi.y = f2bf(v.y);
        hi.z = f2bf(v.z); hi.w = f2bf(v.w);
        const int addr = row * 128 + (((c0 >> 3) ^ (row & 7)) << 3) + (c0 & 7);
        *(us4*)&Xh[addr] = hi;
    }
    __syncthreads();

    // ---- GEMM2 ----
#pragma unroll
    for (int ks = 0; ks < 4; ++ks) {
        const int col0  = 32 * ks + ((lane >> 4) << 3);
        const int aaddr = arow * 128 + (((col0 >> 3) ^ (arow & 7)) << 3);
        ah[ks] = *(const bf16x8*)&Xh[aaddr];
    }
    f32x4 a2[8];
#pragma unroll
    for (int ct = 0; ct < 8; ++ct) a2[ct] = (f32x4){0.f, 0.f, 0.f, 0.f};
#pragma unroll
    for (int ct = 0; ct < 8; ++ct)
#pragma unroll
        for (int ks = 0; ks < 4; ++ks)
            a2[ct] = __builtin_amdgcn_mfma_f32_16x16x32_bf16(ah[ks], wf[ct][ks], a2[ct], 0, 0, 0);

    // ---- epilogue2: bias -> f32 transpose buffer ----
#pragma unroll
    for (int ct = 0; ct < 8; ++ct) {
        const float b2c = b2[16 * ct + (lane & 15)];
#pragma unroll
        for (int r = 0; r < 4; ++r) {
            const int row = 16 * w + ((lane >> 4) << 2) + r;
            OUTB[row * 132 + 16 * ct + (lane & 15)] = a2[ct][r] + b2c;
        }
    }
    __syncthreads();

    // ---- coalesced store (fp16 or f32) + BN stats partials ----
    float ts[4] = {0.f, 0.f, 0.f, 0.f};
    float tq[4] = {0.f, 0.f, 0.f, 0.f};
#pragma unroll
    for (int p = 0; p < 8; ++p) {
        const int  row  = p * 8 + rg;
        const long grow = r0 + row;
        if (MODE == 1 && grow >= NN) continue;
        const float4 v = *(const float4*)&OUTB[row * 132 + c0];
        if (HALFX) {
            __half* xp = (__half*)x2out_v + (size_t)grow * D + c0;
            *(__half2*)(xp)     = __floats2half2_rn(v.x, v.y);
            *(__half2*)(xp + 2) = __floats2half2_rn(v.z, v.w);
        } else {
            *(float4*)((float*)x2out_v + (size_t)grow * D + c0) = v;
        }
        ts[0] += v.x; ts[1] += v.y; ts[2] += v.z; ts[3] += v.w;
        tq[0] += v.x * v.x; tq[1] += v.y * v.y;
        tq[2] += v.z * v.z; tq[3] += v.w * v.w;
    }

    float* red = (float*)Xh;   // Xh fully consumed (16KB >= 3072 floats)
    *(float4*)&red[rg * 128 + c0]        = make_float4(ts[0], ts[1], ts[2], ts[3]);
    *(float4*)&red[1024 + rg * 128 + c0] = make_float4(tq[0], tq[1], tq[2], tq[3]);
    __syncthreads();
    if (tid < 128) {
        float s = 0.f, q = 0.f;
#pragma unroll
        for (int g = 0; g < 8; ++g) {
            s += red[g * 128 + tid];
            q += red[1024 + g * 128 + tid];
        }
        unsafeAtomicAdd(&stats[tid], s);
        unsafeAtomicAdd(&stats[128 + tid], q);
    }
}

// stats layout: [0:128) sum, [128:256) sumsq, [256:384) scale, [384:512) shift
__global__ void bn_finalize_kernel(float* __restrict__ stats,
                                   const float* __restrict__ gamma,
                                   const float* __restrict__ beta,
                                   float inv_count)
{
    const int c = threadIdx.x;
    if (c < D) {
        const float mu  = stats[c] * inv_count;
        const float var = stats[128 + c] * inv_count - mu * mu;
        const float sc  = rsqrtf(var + BN_EPS) * gamma[c];
        stats[256 + c] = sc;
        stats[384 + c] = beta[c] - mu * sc;
    }
}

// ---- CSR build ----
__global__ __launch_bounds__(256) void hist_kernel(
    const int* __restrict__ dst, int* __restrict__ cnt)
{
    const int i = blockIdx.x * 256 + threadIdx.x;
    if (i < NE) atomicAdd(&cnt[dst[i]], 1);
}

__global__ __launch_bounds__(1024) void scan_kernel(
    const int* __restrict__ cnt, int* __restrict__ off)
{
    __shared__ int part[1024];
    const int t = threadIdx.x;
    const int SEG = (NN + 1023) / 1024;
    const int base = t * SEG;

    int s = 0;
    for (int i = 0; i < SEG; ++i) {
        const int idx = base + i;
        if (idx < NN) s += cnt[idx];
    }
    part[t] = s;
    __syncthreads();
    for (int d = 1; d < 1024; d <<= 1) {
        int v = (t >= d) ? part[t - d] : 0;
        __syncthreads();
        part[t] += v;
        __syncthreads();
    }
    int run = (t > 0) ? part[t - 1] : 0;
    for (int i = 0; i < SEG; ++i) {
        const int idx = base + i;
        if (idx < NN) { off[idx] = run; run += cnt[idx]; }
    }
    if (t == 1023) off[NN] = part[1023];
}

__global__ __launch_bounds__(256) void csr_scatter_kernel(
    const int* __restrict__ dst, const int* __restrict__ off,
    int* __restrict__ cnt, int* __restrict__ csr)
{
    const int i = blockIdx.x * 256 + threadIdx.x;
    if (i < NE) {
        const int d = dst[i];
        const int p = atomicSub(&cnt[d], 1) - 1;
        csr[off[d] + p] = i;
    }
}

// ---------------------------------------------------------------------------
// Fused BN-apply + residual + segment-sum gather (R9 version, verified).
// One wave per node; each iteration handles TWO edges (lane>>5 selects edge,
// (lane&31)*4 cols): 16B e loads, 8B x2h loads, 16B stores; cross-half
// combine via shfl_xor(.,32).
// ---------------------------------------------------------------------------
template<int HALFX>
__global__ __launch_bounds__(256) void apply_gather_kernel(
    const float* __restrict__ e, const float* __restrict__ stats,
    const int* __restrict__ off, const int* __restrict__ csr,
    const void* __restrict__ x2src, float* __restrict__ eout,
    float* __restrict__ agg)
{
    const int node = blockIdx.x * 4 + (threadIdx.x >> 6);
    const int lane = threadIdx.x & 63;
    const int half = lane >> 5;
    const int c0   = (lane & 31) * 4;
    if (node >= NN) return;

    const float4 sc = *(const float4*)(stats + 256 + c0);
    const float4 sh = *(const float4*)(stats + 384 + c0);
    float4 acc = make_float4(0.f, 0.f, 0.f, 0.f);
    const int jb = off[node], je = off[node + 1];
    const int niter = (je - jb + 1) >> 1;

#pragma unroll 2
    for (int p = 0; p < niter; ++p) {
        const int j0 = jb + 2 * p + half;
        if (j0 < je) {
            const int eidx = csr[j0];
            const size_t base = (size_t)eidx * D + c0;
            float4 x;
            if (HALFX) {
                const int2 xi = *(const int2*)((const __half*)x2src + base);
                const float2 f0 = __half22float2(*(const __half2*)&xi.x);
                const float2 f1 = __half22float2(*(const __half2*)&xi.y);
                x = make_float4(f0.x, f0.y, f1.x, f1.y);
            } else {
                x = *(const float4*)(eout + base);
            }
            const float4 ev = *(const float4*)(e + base);
            float4 v;
            v.x = fmaf(x.x, sc.x, sh.x) + ev.x;
            v.y = fmaf(x.y, sc.y, sh.y) + ev.y;
            v.z = fmaf(x.z, sc.z, sh.z) + ev.z;
            v.w = fmaf(x.w, sc.w, sh.w) + ev.w;
            *(float4*)(eout + base) = v;
            acc.x += v.x; acc.y += v.y; acc.z += v.z; acc.w += v.w;
        }
    }

    acc.x += __shfl_xor(acc.x, 32);
    acc.y += __shfl_xor(acc.y, 32);
    acc.z += __shfl_xor(acc.z, 32);
    acc.w += __shfl_xor(acc.w, 32);
    if (half == 0)
        *(float4*)(agg + (size_t)node * D + c0) = acc;
}

// h_new = y2*scale + shift + h (in-place over y2 in d_out)
__global__ __launch_bounds__(256) void node_apply_kernel(
    const float* __restrict__ h, const float* __restrict__ stats,
    float* __restrict__ hout)
{
    const int gid = blockIdx.x * 256 + threadIdx.x;
    const int c0  = (gid & 31) * 4;
    const size_t base = (size_t)(gid >> 5) * D + c0;

    const float4 sc = *(const float4*)(stats + 256 + c0);
    const float4 sh = *(const float4*)(stats + 384 + c0);
    const float4 x  = *(const float4*)(hout + base);
    const float4 hv = *(const float4*)(h + base);
    float4 v;
    v.x = fmaf(x.x, sc.x, sh.x) + hv.x;
    v.y = fmaf(x.y, sc.y, sh.y) + hv.y;
    v.z = fmaf(x.z, sc.z, sh.z) + hv.z;
    v.w = fmaf(x.w, sc.w, sh.w) + hv.w;
    *(float4*)(hout + base) = v;
}

extern "C" void kernel_launch(void* const* d_in, const int* in_sizes, int n_in,
                              void* d_out, int out_size, void* d_ws, size_t ws_size,
                              hipStream_t stream)
{
    const float* h   = (const float*)d_in[0];
    const float* e   = (const float*)d_in[1];
    const int*   src = (const int*)d_in[2];
    const int*   dst = (const int*)d_in[3];
    const float* Wa1 = (const float*)d_in[4];
    const float* ba1 = (const float*)d_in[5];
    const float* Wa2 = (const float*)d_in[6];
    const float* ba2 = (const float*)d_in[7];
    const float* Wb1 = (const float*)d_in[8];
    const float* bb1 = (const float*)d_in[9];
    const float* Wb2 = (const float*)d_in[10];
    const float* bb2 = (const float*)d_in[11];
    const float* ga  = (const float*)d_in[12];
    const float* bea = (const float*)d_in[13];
    const float* gb  = (const float*)d_in[14];
    const float* beb = (const float*)d_in[15];

    float* out  = (float*)d_out;
    float* hnew = out;                      // NN*D (y2 scratch, then h_new)
    float* enew = out + (size_t)NN * D;     // NE*D (e_new; x2 scratch if f32 path)

    // ws layout (float units):
    //   estats[512] | nstats[512] | icnt[NN] | ioff[NN+1] | pad3 |
    //   wtb1/wtb2/wta1/wta2 (4 x 16384 ushort) | csr[NE ints] | agg[NN*D] |
    //   x2h[NE*D halves]  (only if ws_size permits)
    float* ws     = (float*)d_ws;
    float* estats = ws;
    float* nstats = ws + 512;
    int*   icnt   = (int*)(ws + 1024);
    int*   ioff   = icnt + NN;
    unsigned short* wtb1 = (unsigned short*)(ioff + NN + 1 + 3);  // 16B aligned
    unsigned short* wtb2 = wtb1 + 16384;
    unsigned short* wta1 = wtb2 + 16384;
    unsigned short* wta2 = wta1 + 16384;
    int*    icsr = (int*)(wta2 + 16384);
    float*  agg  = (float*)(icsr + NE);
    __half* x2h  = (__half*)(agg + (size_t)NN * D);
    const size_t need_half = (size_t)((char*)(x2h + (size_t)NE * D) - (char*)d_ws);
    const bool use_half = (ws_size >= need_half);

    // zero BN stats + histogram counters
    hipMemsetAsync(d_ws, 0, (size_t)(1024 + NN) * sizeof(float), stream);

    // ---- weight prep (fragment-linear bf16) ----
    wprep_kernel<<<64, 256, 0, stream>>>(Wb1, wtb1);
    wprep_kernel<<<64, 256, 0, stream>>>(Wb2, wtb2);
    wprep_kernel<<<64, 256, 0, stream>>>(Wa1, wta1);
    wprep_kernel<<<64, 256, 0, stream>>>(Wa2, wta2);

    // ---- CSR build ----
    hist_kernel<<<(NE + 255) / 256, 256, 0, stream>>>(dst, icnt);
    scan_kernel<<<1, 1024, 0, stream>>>(icnt, ioff);
    csr_scatter_kernel<<<(NE + 255) / 256, 256, 0, stream>>>(dst, ioff, icnt, icsr);

    // ---- bond (edge) path ----
    if (use_half) {
        mlp_mfma_kernel<0, 1><<<NE / 64, 256, 0, stream>>>(
            h, e, src, dst, wtb1, bb1, wtb2, bb2, (void*)x2h, estats);
        bn_finalize_kernel<<<1, 128, 0, stream>>>(estats, gb, beb, 1.0f / NE);
        apply_gather_kernel<1><<<(NN + 3) / 4, 256, 0, stream>>>(
            e, estats, ioff, icsr, (const void*)x2h, enew, agg);
    } else {
        mlp_mfma_kernel<0, 0><<<NE / 64, 256, 0, stream>>>(
            h, e, src, dst, wtb1, bb1, wtb2, bb2, (void*)enew, estats);
        bn_finalize_kernel<<<1, 128, 0, stream>>>(estats, gb, beb, 1.0f / NE);
        apply_gather_kernel<0><<<(NN + 3) / 4, 256, 0, stream>>>(
            e, estats, ioff, icsr, nullptr, enew, agg);
    }

    // ---- atom (node) path ----
    mlp_mfma_kernel<1, 0><<<(NN + 63) / 64, 256, 0, stream>>>(
        h, agg, nullptr, nullptr, wta1, ba1, wta2, ba2, (void*)hnew, nstats);
    bn_finalize_kernel<<<1, 128, 0, stream>>>(nstats, ga, bea, 1.0f / NN);
    node_apply_kernel<<<(NN * 32) / 256, 256, 0, stream>>>(h, nstats, hnew);
}

// Round 16
// 804.243 us; speedup vs baseline: 1.2148x; 1.2148x over previous
//
#include <hip/hip_runtime.h>
#include <hip/hip_fp16.h>
#include <cstddef>

#define NN 50000
#define NE 800000
#define D 128
#define BN_EPS 1e-5f

typedef __attribute__((ext_vector_type(8))) short bf16x8;
typedef __attribute__((ext_vector_type(4))) float f32x4;
typedef __attribute__((ext_vector_type(4))) unsigned short us4;

__device__ __forceinline__ unsigned short f2bf(float x) {
    unsigned u = __float_as_uint(x);
    return (unsigned short)((u + 0x7fffu + ((u >> 16) & 1u)) >> 16);  // RNE
}

// ---------------------------------------------------------------------------
// W prep: W[k][n] f32 -> fragment-linear bf16 Wt (verified R2: B-operand frag)
// ---------------------------------------------------------------------------
__global__ __launch_bounds__(256) void wprep_kernel(
    const float* __restrict__ W, unsigned short* __restrict__ Wt)
{
    const int idx = blockIdx.x * 256 + threadIdx.x;   // [0, 16384)
    const int j  = idx & 7;
    const int l  = (idx >> 3) & 63;
    const int ks = (idx >> 9) & 3;
    const int ct = (idx >> 11) & 7;
    const int n  = 16 * ct + (l & 15);
    const int k  = 32 * ks + ((l >> 4) << 3) + j;
    Wt[idx] = f2bf(W[k * 128 + n]);
}

// ---------------------------------------------------------------------------
// R7 structure + single-bf16 X/Y (accuracy 0.047 verified R10) with LDS
// padded to 57KB to pin occupancy at 2 blocks/CU (R10's 3 blocks/CU blew
// the per-XCD L2: FETCH 569->867MB, WRITE 213->778MB). Packed 8B fp16 row
// stores. In-kernel OUTB-based BN stats (R7-proven).
// MODE 0 (edge): X = e+h[src]+h[dst]. MODE 1 (node): X = h+agg (guarded).
// ---------------------------------------------------------------------------
template<int MODE, int HALFX>
__global__ __launch_bounds__(256, 2) void mlp_mfma_kernel(
    const float* __restrict__ h, const float* __restrict__ e_or_agg,
    const int* __restrict__ src, const int* __restrict__ dst,
    const unsigned short* __restrict__ Wt1, const float* __restrict__ b1,
    const unsigned short* __restrict__ Wt2, const float* __restrict__ b2,
    void* __restrict__ x2out_v, float* __restrict__ stats)
{
    __shared__ __align__(16) unsigned short Xh[8192];        // 16 KB
    __shared__ __align__(16) float OUTB[64 * 132 + 2048];    // 41.8 KB (padded)
    // total 57.8 KB -> exactly 2 blocks/CU on 160KB LDS

    const int tid  = threadIdx.x;
    const int lane = tid & 63;
    const int w    = tid >> 6;        // wave id 0..3 -> rows 16w..16w+15
    const int cg   = tid & 31;
    const int rg   = tid >> 5;
    const int c0   = cg * 4;
    const long r0  = (long)blockIdx.x * 64;

    // keep the pad alive without ever executing the store
    if (stats == (float*)1) OUTB[64 * 132 + (tid & 2047)] = 1.f;

    // ---- W1 fragments -> VGPRs ----
    const bf16x8* Wg1 = (const bf16x8*)Wt1;
    bf16x8 wf[8][4];
#pragma unroll
    for (int ct = 0; ct < 8; ++ct)
#pragma unroll
        for (int ks = 0; ks < 4; ++ks)
            wf[ct][ks] = Wg1[(ct * 4 + ks) * 64 + lane];

    // ---- stage X as single bf16 into swizzled LDS ----
#pragma unroll
    for (int p = 0; p < 8; ++p) {
        const int  row  = p * 8 + rg;
        const long grow = r0 + row;
        float4 v = make_float4(0.f, 0.f, 0.f, 0.f);
        if (MODE == 0) {
            const int sN = src[grow];
            const int dN = dst[grow];
            const float4 ev = *(const float4*)(e_or_agg + (size_t)grow * D + c0);
            const float4 hs = *(const float4*)(h + (size_t)sN * D + c0);
            const float4 hd = *(const float4*)(h + (size_t)dN * D + c0);
            v.x = ev.x + hs.x + hd.x; v.y = ev.y + hs.y + hd.y;
            v.z = ev.z + hs.z + hd.z; v.w = ev.w + hs.w + hd.w;
        } else {
            if (grow < NN) {
                const float4 hv = *(const float4*)(h + (size_t)grow * D + c0);
                const float4 av = *(const float4*)(e_or_agg + (size_t)grow * D + c0);
                v.x = hv.x + av.x; v.y = hv.y + av.y;
                v.z = hv.z + av.z; v.w = hv.w + av.w;
            }
        }
        us4 hi;
        hi.x = f2bf(v.x); hi.y = f2bf(v.y);
        hi.z = f2bf(v.z); hi.w = f2bf(v.w);
        const int addr = row * 128 + (((c0 >> 3) ^ (row & 7)) << 3) + (c0 & 7);
        *(us4*)&Xh[addr] = hi;
    }
    __syncthreads();

    // ---- GEMM1 ----
    const int arow = 16 * w + (lane & 15);
    bf16x8 ah[4];
#pragma unroll
    for (int ks = 0; ks < 4; ++ks) {
        const int col0  = 32 * ks + ((lane >> 4) << 3);
        const int aaddr = arow * 128 + (((col0 >> 3) ^ (arow & 7)) << 3);
        ah[ks] = *(const bf16x8*)&Xh[aaddr];
    }
    f32x4 acc[8];
#pragma unroll
    for (int ct = 0; ct < 8; ++ct) acc[ct] = (f32x4){0.f, 0.f, 0.f, 0.f};
#pragma unroll
    for (int ct = 0; ct < 8; ++ct)
#pragma unroll
        for (int ks = 0; ks < 4; ++ks)
            acc[ct] = __builtin_amdgcn_mfma_f32_16x16x32_bf16(ah[ks], wf[ct][ks], acc[ct], 0, 0, 0);

    // ---- issue W2 loads (overwrite wf) ----
    const bf16x8* Wg2 = (const bf16x8*)Wt2;
#pragma unroll
    for (int ct = 0; ct < 8; ++ct)
#pragma unroll
        for (int ks = 0; ks < 4; ++ks)
            wf[ct][ks] = Wg2[(ct * 4 + ks) * 64 + lane];

    // ---- epilogue1: bias + relu -> f32 transpose buffer ----
#pragma unroll
    for (int ct = 0; ct < 8; ++ct) {
        const float b1c = b1[16 * ct + (lane & 15)];
#pragma unroll
        for (int r = 0; r < 4; ++r) {
            const int row = 16 * w + ((lane >> 4) << 2) + r;
            OUTB[row * 132 + 16 * ct + (lane & 15)] = fmaxf(acc[ct][r] + b1c, 0.f);
        }
    }
    __syncthreads();

    // ---- restage Y as single bf16 ----
#pragma unroll
    for (int p = 0; p < 8; ++p) {
        const int row = p * 8 + rg;
        const float4 v = *(const float4*)&OUTB[row * 132 + c0];
        us4 hi;
        hi.x = f2bf(v.x); hi.y = f2bf(v.y);
        hi.z = f2bf(v.z); hi.w = f2bf(v.w);
        const int addr = row * 128 + (((c0 >> 3) ^ (row & 7)) << 3) + (c0 & 7);
        *(us4*)&Xh[addr] = hi;
    }
    __syncthreads();

    // ---- GEMM2 ----
#pragma unroll
    for (int ks = 0; ks < 4; ++ks) {
        const int col0  = 32 * ks + ((lane >> 4) << 3);
        const int aaddr = arow * 128 + (((col0 >> 3) ^ (arow & 7)) << 3);
        ah[ks] = *(const bf16x8*)&Xh[aaddr];
    }
    f32x4 a2[8];
#pragma unroll
    for (int ct = 0; ct < 8; ++ct) a2[ct] = (f32x4){0.f, 0.f, 0.f, 0.f};
#pragma unroll
    for (int ct = 0; ct < 8; ++ct)
#pragma unroll
        for (int ks = 0; ks < 4; ++ks)
            a2[ct] = __builtin_amdgcn_mfma_f32_16x16x32_bf16(ah[ks], wf[ct][ks], a2[ct], 0, 0, 0);

    // ---- epilogue2: bias -> f32 transpose buffer ----
#pragma unroll
    for (int ct = 0; ct < 8; ++ct) {
        const float b2c = b2[16 * ct + (lane & 15)];
#pragma unroll
        for (int r = 0; r < 4; ++r) {
            const int row = 16 * w + ((lane >> 4) << 2) + r;
            OUTB[row * 132 + 16 * ct + (lane & 15)] = a2[ct][r] + b2c;
        }
    }
    __syncthreads();

    // ---- coalesced store (packed 8B fp16 or 16B f32) + BN stats ----
    float ts[4] = {0.f, 0.f, 0.f, 0.f};
    float tq[4] = {0.f, 0.f, 0.f, 0.f};
#pragma unroll
    for (int p = 0; p < 8; ++p) {
        const int  row  = p * 8 + rg;
        const long grow = r0 + row;
        if (MODE == 1 && grow >= NN) continue;
        const float4 v = *(const float4*)&OUTB[row * 132 + c0];
        if (HALFX) {
            const __half2 h0 = __floats2half2_rn(v.x, v.y);
            const __half2 h1 = __floats2half2_rn(v.z, v.w);
            int2 pk;
            pk.x = *(const int*)&h0;
            pk.y = *(const int*)&h1;
            *(int2*)((__half*)x2out_v + (size_t)grow * D + c0) = pk;
        } else {
            *(float4*)((float*)x2out_v + (size_t)grow * D + c0) = v;
        }
        ts[0] += v.x; ts[1] += v.y; ts[2] += v.z; ts[3] += v.w;
        tq[0] += v.x * v.x; tq[1] += v.y * v.y;
        tq[2] += v.z * v.z; tq[3] += v.w * v.w;
    }

    float* red = (float*)Xh;   // Xh fully consumed (16KB >= 2048 floats)
    *(float4*)&red[rg * 128 + c0]        = make_float4(ts[0], ts[1], ts[2], ts[3]);
    *(float4*)&red[1024 + rg * 128 + c0] = make_float4(tq[0], tq[1], tq[2], tq[3]);
    __syncthreads();
    if (tid < 128) {
        float s = 0.f, q = 0.f;
#pragma unroll
        for (int g = 0; g < 8; ++g) {
            s += red[g * 128 + tid];
            q += red[1024 + g * 128 + tid];
        }
        unsafeAtomicAdd(&stats[tid], s);
        unsafeAtomicAdd(&stats[128 + tid], q);
    }
}

// stats layout: [0:128) sum, [128:256) sumsq, [256:384) scale, [384:512) shift
__global__ void bn_finalize_kernel(float* __restrict__ stats,
                                   const float* __restrict__ gamma,
                                   const float* __restrict__ beta,
                                   float inv_count)
{
    const int c = threadIdx.x;
    if (c < D) {
        const float mu  = stats[c] * inv_count;
        const float var = stats[128 + c] * inv_count - mu * mu;
        const float sc  = rsqrtf(var + BN_EPS) * gamma[c];
        stats[256 + c] = sc;
        stats[384 + c] = beta[c] - mu * sc;
    }
}

// ---- CSR build ----
__global__ __launch_bounds__(256) void hist_kernel(
    const int* __restrict__ dst, int* __restrict__ cnt)
{
    const int i = blockIdx.x * 256 + threadIdx.x;
    if (i < NE) atomicAdd(&cnt[dst[i]], 1);
}

__global__ __launch_bounds__(1024) void scan_kernel(
    const int* __restrict__ cnt, int* __restrict__ off)
{
    __shared__ int part[1024];
    const int t = threadIdx.x;
    const int SEG = (NN + 1023) / 1024;
    const int base = t * SEG;

    int s = 0;
    for (int i = 0; i < SEG; ++i) {
        const int idx = base + i;
        if (idx < NN) s += cnt[idx];
    }
    part[t] = s;
    __syncthreads();
    for (int d = 1; d < 1024; d <<= 1) {
        int v = (t >= d) ? part[t - d] : 0;
        __syncthreads();
        part[t] += v;
        __syncthreads();
    }
    int run = (t > 0) ? part[t - 1] : 0;
    for (int i = 0; i < SEG; ++i) {
        const int idx = base + i;
        if (idx < NN) { off[idx] = run; run += cnt[idx]; }
    }
    if (t == 1023) off[NN] = part[1023];
}

__global__ __launch_bounds__(256) void csr_scatter_kernel(
    const int* __restrict__ dst, const int* __restrict__ off,
    int* __restrict__ cnt, int* __restrict__ csr)
{
    const int i = blockIdx.x * 256 + threadIdx.x;
    if (i < NE) {
        const int d = dst[i];
        const int p = atomicSub(&cnt[d], 1) - 1;
        csr[off[d] + p] = i;
    }
}

// ---------------------------------------------------------------------------
// Fused BN-apply + residual + segment-sum gather (R9 version, verified).
// ---------------------------------------------------------------------------
template<int HALFX>
__global__ __launch_bounds__(256) void apply_gather_kernel(
    const float* __restrict__ e, const float* __restrict__ stats,
    const int* __restrict__ off, const int* __restrict__ csr,
    const void* __restrict__ x2src, float* __restrict__ eout,
    float* __restrict__ agg)
{
    const int node = blockIdx.x * 4 + (threadIdx.x >> 6);
    const int lane = threadIdx.x & 63;
    const int half = lane >> 5;
    const int c0   = (lane & 31) * 4;
    if (node >= NN) return;

    const float4 sc = *(const float4*)(stats + 256 + c0);
    const float4 sh = *(const float4*)(stats + 384 + c0);
    float4 acc = make_float4(0.f, 0.f, 0.f, 0.f);
    const int jb = off[node], je = off[node + 1];
    const int niter = (je - jb + 1) >> 1;

#pragma unroll 2
    for (int p = 0; p < niter; ++p) {
        const int j0 = jb + 2 * p + half;
        if (j0 < je) {
            const int eidx = csr[j0];
            const size_t base = (size_t)eidx * D + c0;
            float4 x;
            if (HALFX) {
                const int2 xi = *(const int2*)((const __half*)x2src + base);
                const float2 f0 = __half22float2(*(const __half2*)&xi.x);
                const float2 f1 = __half22float2(*(const __half2*)&xi.y);
                x = make_float4(f0.x, f0.y, f1.x, f1.y);
            } else {
                x = *(const float4*)(eout + base);
            }
            const float4 ev = *(const float4*)(e + base);
            float4 v;
            v.x = fmaf(x.x, sc.x, sh.x) + ev.x;
            v.y = fmaf(x.y, sc.y, sh.y) + ev.y;
            v.z = fmaf(x.z, sc.z, sh.z) + ev.z;
            v.w = fmaf(x.w, sc.w, sh.w) + ev.w;
            *(float4*)(eout + base) = v;
            acc.x += v.x; acc.y += v.y; acc.z += v.z; acc.w += v.w;
        }
    }

    acc.x += __shfl_xor(acc.x, 32);
    acc.y += __shfl_xor(acc.y, 32);
    acc.z += __shfl_xor(acc.z, 32);
    acc.w += __shfl_xor(acc.w, 32);
    if (half == 0)
        *(float4*)(agg + (size_t)node * D + c0) = acc;
}

// h_new = y2*scale + shift + h (in-place over y2 in d_out)
__global__ __launch_bounds__(256) void node_apply_kernel(
    const float* __restrict__ h, const float* __restrict__ stats,
    float* __restrict__ hout)
{
    const int gid = blockIdx.x * 256 + threadIdx.x;
    const int c0  = (gid & 31) * 4;
    const size_t base = (size_t)(gid >> 5) * D + c0;

    const float4 sc = *(const float4*)(stats + 256 + c0);
    const float4 sh = *(const float4*)(stats + 384 + c0);
    const float4 x  = *(const float4*)(hout + base);
    const float4 hv = *(const float4*)(h + base);
    float4 v;
    v.x = fmaf(x.x, sc.x, sh.x) + hv.x;
    v.y = fmaf(x.y, sc.y, sh.y) + hv.y;
    v.z = fmaf(x.z, sc.z, sh.z) + hv.z;
    v.w = fmaf(x.w, sc.w, sh.w) + hv.w;
    *(float4*)(hout + base) = v;
}

extern "C" void kernel_launch(void* const* d_in, const int* in_sizes, int n_in,
                              void* d_out, int out_size, void* d_ws, size_t ws_size,
                              hipStream_t stream)
{
    const float* h   = (const float*)d_in[0];
    const float* e   = (const float*)d_in[1];
    const int*   src = (const int*)d_in[2];
    const int*   dst = (const int*)d_in[3];
    const float* Wa1 = (const float*)d_in[4];
    const float* ba1 = (const float*)d_in[5];
    const float* Wa2 = (const float*)d_in[6];
    const float* ba2 = (const float*)d_in[7];
    const float* Wb1 = (const float*)d_in[8];
    const float* bb1 = (const float*)d_in[9];
    const float* Wb2 = (const float*)d_in[10];
    const float* bb2 = (const float*)d_in[11];
    const float* ga  = (const float*)d_in[12];
    const float* bea = (const float*)d_in[13];
    const float* gb  = (const float*)d_in[14];
    const float* beb = (const float*)d_in[15];

    float* out  = (float*)d_out;
    float* hnew = out;                      // NN*D (y2 scratch, then h_new)
    float* enew = out + (size_t)NN * D;     // NE*D (e_new; x2 scratch if f32 path)

    // ws layout (float units):
    //   estats[512] | nstats[512] | icnt[NN] | ioff[NN+1] | pad3 |
    //   wtb1/wtb2/wta1/wta2 (4 x 16384 ushort) | csr[NE ints] | agg[NN*D] |
    //   x2h[NE*D halves]  (only if ws_size permits)
    float* ws     = (float*)d_ws;
    float* estats = ws;
    float* nstats = ws + 512;
    int*   icnt   = (int*)(ws + 1024);
    int*   ioff   = icnt + NN;
    unsigned short* wtb1 = (unsigned short*)(ioff + NN + 1 + 3);  // 16B aligned
    unsigned short* wtb2 = wtb1 + 16384;
    unsigned short* wta1 = wtb2 + 16384;
    unsigned short* wta2 = wta1 + 16384;
    int*    icsr = (int*)(wta2 + 16384);
    float*  agg  = (float*)(icsr + NE);
    __half* x2h  = (__half*)(agg + (size_t)NN * D);
    const size_t need_half = (size_t)((char*)(x2h + (size_t)NE * D) - (char*)d_ws);
    const bool use_half = (ws_size >= need_half);

    // zero BN stats + histogram counters
    hipMemsetAsync(d_ws, 0, (size_t)(1024 + NN) * sizeof(float), stream);

    // ---- weight prep (fragment-linear bf16) ----
    wprep_kernel<<<64, 256, 0, stream>>>(Wb1, wtb1);
    wprep_kernel<<<64, 256, 0, stream>>>(Wb2, wtb2);
    wprep_kernel<<<64, 256, 0, stream>>>(Wa1, wta1);
    wprep_kernel<<<64, 256, 0, stream>>>(Wa2, wta2);

    // ---- CSR build ----
    hist_kernel<<<(NE + 255) / 256, 256, 0, stream>>>(dst, icnt);
    scan_kernel<<<1, 1024, 0, stream>>>(icnt, ioff);
    csr_scatter_kernel<<<(NE + 255) / 256, 256, 0, stream>>>(dst, ioff, icnt, icsr);

    // ---- bond (edge) path ----
    if (use_half) {
        mlp_mfma_kernel<0, 1><<<NE / 64, 256, 0, stream>>>(
            h, e, src, dst, wtb1, bb1, wtb2, bb2, (void*)x2h, estats);
        bn_finalize_kernel<<<1, 128, 0, stream>>>(estats, gb, beb, 1.0f / NE);
        apply_gather_kernel<1><<<(NN + 3) / 4, 256, 0, stream>>>(
            e, estats, ioff, icsr, (const void*)x2h, enew, agg);
    } else {
        mlp_mfma_kernel<0, 0><<<NE / 64, 256, 0, stream>>>(
            h, e, src, dst, wtb1, bb1, wtb2, bb2, (void*)enew, estats);
        bn_finalize_kernel<<<1, 128, 0, stream>>>(estats, gb, beb, 1.0f / NE);
        apply_gather_kernel<0><<<(NN + 3) / 4, 256, 0, stream>>>(
            e, estats, ioff, icsr, nullptr, enew, agg);
    }

    // ---- atom (node) path ----
    mlp_mfma_kernel<1, 0><<<(NN + 63) / 64, 256, 0, stream>>>(
        h, agg, nullptr, nullptr, wta1, ba1, wta2, ba2, (void*)hnew, nstats);
    bn_finalize_kernel<<<1, 128, 0, stream>>>(nstats, ga, bea, 1.0f / NN);
    node_apply_kernel<<<(NN * 32) / 256, 256, 0, stream>>>(h, nstats, hnew);
}

// Round 17
// 803.174 us; speedup vs baseline: 1.2164x; 1.0013x over previous
//
#include <hip/hip_runtime.h>
#include <hip/hip_fp16.h>
#include <cstddef>

#define NN 50000
#define NE 800000
#define D 128
#define BN_EPS 1e-5f

typedef __attribute__((ext_vector_type(8))) short bf16x8;
typedef __attribute__((ext_vector_type(4))) float f32x4;
typedef __attribute__((ext_vector_type(4))) unsigned short us4;

__device__ __forceinline__ unsigned short f2bf(float x) {
    unsigned u = __float_as_uint(x);
    return (unsigned short)((u + 0x7fffu + ((u >> 16) & 1u)) >> 16);  // RNE
}

// ---------------------------------------------------------------------------
// W prep: W[k][n] f32 -> fragment-linear bf16 Wt (verified R2: B-operand frag)
// ---------------------------------------------------------------------------
__global__ __launch_bounds__(256) void wprep_kernel(
    const float* __restrict__ W, unsigned short* __restrict__ Wt)
{
    const int idx = blockIdx.x * 256 + threadIdx.x;   // [0, 16384)
    const int j  = idx & 7;
    const int l  = (idx >> 3) & 63;
    const int ks = (idx >> 9) & 3;
    const int ct = (idx >> 11) & 7;
    const int n  = 16 * ct + (l & 15);
    const int k  = 32 * ks + ((l >> 4) << 3) + j;
    Wt[idx] = f2bf(W[k * 128 + n]);
}

// ---------------------------------------------------------------------------
// R11 structure (single-bf16, swizzled Xh LDS, OUTB transpose, in-kernel BN
// stats, fp16 x2 out, LDS padded -> 2 blocks/CU) with 512-THREAD BLOCKS over
// the same 64-row tile: waves 0-3 own cols 0-63, waves 4-7 own cols 64-127.
// Same L2 working set (128 rows/CU) but 4 waves/SIMD instead of 2, and each
// wave's serial chain halves (16 MFMA/GEMM, wf[4][4]).
// MODE 0 (edge): X = e+h[src]+h[dst]. MODE 1 (node): X = h+agg (guarded).
// ---------------------------------------------------------------------------
template<int MODE, int HALFX>
__global__ __launch_bounds__(512, 4) void mlp_mfma_kernel(
    const float* __restrict__ h, const float* __restrict__ e_or_agg,
    const int* __restrict__ src, const int* __restrict__ dst,
    const unsigned short* __restrict__ Wt1, const float* __restrict__ b1,
    const unsigned short* __restrict__ Wt2, const float* __restrict__ b2,
    void* __restrict__ x2out_v, float* __restrict__ stats)
{
    __shared__ __align__(16) unsigned short Xh[8192];        // 16 KB
    __shared__ __align__(16) float OUTB[64 * 132 + 2048];    // 41.8 KB (padded)
    // total 57.8 KB -> exactly 2 blocks/CU (1024 threads, 16 waves, 4/SIMD)

    const int tid  = threadIdx.x;
    const int lane = tid & 63;
    const int w    = tid >> 6;        // 0..7
    const int wq   = w & 3;           // row quad -> rows 16wq..16wq+15
    const int wh   = w >> 2;          // col half -> ct tiles 4wh..4wh+3
    const int cg   = tid & 31;
    const int rg   = tid >> 5;        // 0..15
    const int c0   = cg * 4;
    const long r0  = (long)blockIdx.x * 64;

    // keep the pad alive without ever executing the store
    if (stats == (float*)1) OUTB[64 * 132 + (tid & 2047)] = 1.f;

    // ---- W1 fragments (this wave's 4 col-tiles) -> VGPRs ----
    const bf16x8* Wg1 = (const bf16x8*)Wt1;
    bf16x8 wf[4][4];
#pragma unroll
    for (int ctl = 0; ctl < 4; ++ctl)
#pragma unroll
        for (int ks = 0; ks < 4; ++ks)
            wf[ctl][ks] = Wg1[((4 * wh + ctl) * 4 + ks) * 64 + lane];

    // ---- stage X as single bf16 into swizzled LDS (512 threads, 4 rows ea) ----
#pragma unroll
    for (int p = 0; p < 4; ++p) {
        const int  row  = p * 16 + rg;
        const long grow = r0 + row;
        float4 v = make_float4(0.f, 0.f, 0.f, 0.f);
        if (MODE == 0) {
            const int sN = src[grow];
            const int dN = dst[grow];
            const float4 ev = *(const float4*)(e_or_agg + (size_t)grow * D + c0);
            const float4 hs = *(const float4*)(h + (size_t)sN * D + c0);
            const float4 hd = *(const float4*)(h + (size_t)dN * D + c0);
            v.x = ev.x + hs.x + hd.x; v.y = ev.y + hs.y + hd.y;
            v.z = ev.z + hs.z + hd.z; v.w = ev.w + hs.w + hd.w;
        } else {
            if (grow < NN) {
                const float4 hv = *(const float4*)(h + (size_t)grow * D + c0);
                const float4 av = *(const float4*)(e_or_agg + (size_t)grow * D + c0);
                v.x = hv.x + av.x; v.y = hv.y + av.y;
                v.z = hv.z + av.z; v.w = hv.w + av.w;
            }
        }
        us4 hi;
        hi.x = f2bf(v.x); hi.y = f2bf(v.y);
        hi.z = f2bf(v.z); hi.w = f2bf(v.w);
        const int addr = row * 128 + (((c0 >> 3) ^ (row & 7)) << 3) + (c0 & 7);
        *(us4*)&Xh[addr] = hi;
    }
    __syncthreads();

    // ---- GEMM1 (16 MFMA) ----
    const int arow = 16 * wq + (lane & 15);
    bf16x8 ah[4];
#pragma unroll
    for (int ks = 0; ks < 4; ++ks) {
        const int col0  = 32 * ks + ((lane >> 4) << 3);
        const int aaddr = arow * 128 + (((col0 >> 3) ^ (arow & 7)) << 3);
        ah[ks] = *(const bf16x8*)&Xh[aaddr];
    }
    f32x4 acc[4];
#pragma unroll
    for (int ctl = 0; ctl < 4; ++ctl) acc[ctl] = (f32x4){0.f, 0.f, 0.f, 0.f};
#pragma unroll
    for (int ctl = 0; ctl < 4; ++ctl)
#pragma unroll
        for (int ks = 0; ks < 4; ++ks)
            acc[ctl] = __builtin_amdgcn_mfma_f32_16x16x32_bf16(ah[ks], wf[ctl][ks], acc[ctl], 0, 0, 0);

    // ---- issue W2 loads (overwrite wf) ----
    const bf16x8* Wg2 = (const bf16x8*)Wt2;
#pragma unroll
    for (int ctl = 0; ctl < 4; ++ctl)
#pragma unroll
        for (int ks = 0; ks < 4; ++ks)
            wf[ctl][ks] = Wg2[((4 * wh + ctl) * 4 + ks) * 64 + lane];

    // ---- epilogue1: bias + relu -> OUTB (wave's 64-col half) ----
#pragma unroll
    for (int ctl = 0; ctl < 4; ++ctl) {
        const int ct = 4 * wh + ctl;
        const float b1c = b1[16 * ct + (lane & 15)];
#pragma unroll
        for (int r = 0; r < 4; ++r) {
            const int row = 16 * wq + ((lane >> 4) << 2) + r;
            OUTB[row * 132 + 16 * ct + (lane & 15)] = fmaxf(acc[ctl][r] + b1c, 0.f);
        }
    }
    __syncthreads();

    // ---- restage Y as single bf16 ----
#pragma unroll
    for (int p = 0; p < 4; ++p) {
        const int row = p * 16 + rg;
        const float4 v = *(const float4*)&OUTB[row * 132 + c0];
        us4 hi;
        hi.x = f2bf(v.x); hi.y = f2bf(v.y);
        hi.z = f2bf(v.z); hi.w = f2bf(v.w);
        const int addr = row * 128 + (((c0 >> 3) ^ (row & 7)) << 3) + (c0 & 7);
        *(us4*)&Xh[addr] = hi;
    }
    __syncthreads();

    // ---- GEMM2 (16 MFMA) ----
#pragma unroll
    for (int ks = 0; ks < 4; ++ks) {
        const int col0  = 32 * ks + ((lane >> 4) << 3);
        const int aaddr = arow * 128 + (((col0 >> 3) ^ (arow & 7)) << 3);
        ah[ks] = *(const bf16x8*)&Xh[aaddr];
    }
    f32x4 a2[4];
#pragma unroll
    for (int ctl = 0; ctl < 4; ++ctl) a2[ctl] = (f32x4){0.f, 0.f, 0.f, 0.f};
#pragma unroll
    for (int ctl = 0; ctl < 4; ++ctl)
#pragma unroll
        for (int ks = 0; ks < 4; ++ks)
            a2[ctl] = __builtin_amdgcn_mfma_f32_16x16x32_bf16(ah[ks], wf[ctl][ks], a2[ctl], 0, 0, 0);

    // ---- epilogue2: bias -> OUTB ----
#pragma unroll
    for (int ctl = 0; ctl < 4; ++ctl) {
        const int ct = 4 * wh + ctl;
        const float b2c = b2[16 * ct + (lane & 15)];
#pragma unroll
        for (int r = 0; r < 4; ++r) {
            const int row = 16 * wq + ((lane >> 4) << 2) + r;
            OUTB[row * 132 + 16 * ct + (lane & 15)] = a2[ctl][r] + b2c;
        }
    }
    __syncthreads();

    // ---- coalesced store (packed 8B fp16 or 16B f32) + BN stats ----
    float ts[4] = {0.f, 0.f, 0.f, 0.f};
    float tq[4] = {0.f, 0.f, 0.f, 0.f};
#pragma unroll
    for (int p = 0; p < 4; ++p) {
        const int  row  = p * 16 + rg;
        const long grow = r0 + row;
        if (MODE == 1 && grow >= NN) continue;
        const float4 v = *(const float4*)&OUTB[row * 132 + c0];
        if (HALFX) {
            const __half2 h0 = __floats2half2_rn(v.x, v.y);
            const __half2 h1 = __floats2half2_rn(v.z, v.w);
            int2 pk;
            pk.x = *(const int*)&h0;
            pk.y = *(const int*)&h1;
            *(int2*)((__half*)x2out_v + (size_t)grow * D + c0) = pk;
        } else {
            *(float4*)((float*)x2out_v + (size_t)grow * D + c0) = v;
        }
        ts[0] += v.x; ts[1] += v.y; ts[2] += v.z; ts[3] += v.w;
        tq[0] += v.x * v.x; tq[1] += v.y * v.y;
        tq[2] += v.z * v.z; tq[3] += v.w * v.w;
    }

    float* red = (float*)Xh;   // Xh fully consumed; need 4096 floats = 16KB
    *(float4*)&red[rg * 128 + c0]        = make_float4(ts[0], ts[1], ts[2], ts[3]);
    *(float4*)&red[2048 + rg * 128 + c0] = make_float4(tq[0], tq[1], tq[2], tq[3]);
    __syncthreads();
    if (tid < 128) {
        float s = 0.f, q = 0.f;
#pragma unroll
        for (int g = 0; g < 16; ++g) {
            s += red[g * 128 + tid];
            q += red[2048 + g * 128 + tid];
        }
        unsafeAtomicAdd(&stats[tid], s);
        unsafeAtomicAdd(&stats[128 + tid], q);
    }
}

// stats layout: [0:128) sum, [128:256) sumsq, [256:384) scale, [384:512) shift
__global__ void bn_finalize_kernel(float* __restrict__ stats,
                                   const float* __restrict__ gamma,
                                   const float* __restrict__ beta,
                                   float inv_count)
{
    const int c = threadIdx.x;
    if (c < D) {
        const float mu  = stats[c] * inv_count;
        const float var = stats[128 + c] * inv_count - mu * mu;
        const float sc  = rsqrtf(var + BN_EPS) * gamma[c];
        stats[256 + c] = sc;
        stats[384 + c] = beta[c] - mu * sc;
    }
}

// ---- CSR build ----
__global__ __launch_bounds__(256) void hist_kernel(
    const int* __restrict__ dst, int* __restrict__ cnt)
{
    const int i = blockIdx.x * 256 + threadIdx.x;
    if (i < NE) atomicAdd(&cnt[dst[i]], 1);
}

__global__ __launch_bounds__(1024) void scan_kernel(
    const int* __restrict__ cnt, int* __restrict__ off)
{
    __shared__ int part[1024];
    const int t = threadIdx.x;
    const int SEG = (NN + 1023) / 1024;
    const int base = t * SEG;

    int s = 0;
    for (int i = 0; i < SEG; ++i) {
        const int idx = base + i;
        if (idx < NN) s += cnt[idx];
    }
    part[t] = s;
    __syncthreads();
    for (int d = 1; d < 1024; d <<= 1) {
        int v = (t >= d) ? part[t - d] : 0;
        __syncthreads();
        part[t] += v;
        __syncthreads();
    }
    int run = (t > 0) ? part[t - 1] : 0;
    for (int i = 0; i < SEG; ++i) {
        const int idx = base + i;
        if (idx < NN) { off[idx] = run; run += cnt[idx]; }
    }
    if (t == 1023) off[NN] = part[1023];
}

__global__ __launch_bounds__(256) void csr_scatter_kernel(
    const int* __restrict__ dst, const int* __restrict__ off,
    int* __restrict__ cnt, int* __restrict__ csr)
{
    const int i = blockIdx.x * 256 + threadIdx.x;
    if (i < NE) {
        const int d = dst[i];
        const int p = atomicSub(&cnt[d], 1) - 1;
        csr[off[d] + p] = i;
    }
}

// ---------------------------------------------------------------------------
// Fused BN-apply + residual + segment-sum gather (R9 structure, unroll 4).
// ---------------------------------------------------------------------------
template<int HALFX>
__global__ __launch_bounds__(256) void apply_gather_kernel(
    const float* __restrict__ e, const float* __restrict__ stats,
    const int* __restrict__ off, const int* __restrict__ csr,
    const void* __restrict__ x2src, float* __restrict__ eout,
    float* __restrict__ agg)
{
    const int node = blockIdx.x * 4 + (threadIdx.x >> 6);
    const int lane = threadIdx.x & 63;
    const int half = lane >> 5;
    const int c0   = (lane & 31) * 4;
    if (node >= NN) return;

    const float4 sc = *(const float4*)(stats + 256 + c0);
    const float4 sh = *(const float4*)(stats + 384 + c0);
    float4 acc = make_float4(0.f, 0.f, 0.f, 0.f);
    const int jb = off[node], je = off[node + 1];
    const int niter = (je - jb + 1) >> 1;

#pragma unroll 4
    for (int p = 0; p < niter; ++p) {
        const int j0 = jb + 2 * p + half;
        if (j0 < je) {
            const int eidx = csr[j0];
            const size_t base = (size_t)eidx * D + c0;
            float4 x;
            if (HALFX) {
                const int2 xi = *(const int2*)((const __half*)x2src + base);
                const float2 f0 = __half22float2(*(const __half2*)&xi.x);
                const float2 f1 = __half22float2(*(const __half2*)&xi.y);
                x = make_float4(f0.x, f0.y, f1.x, f1.y);
            } else {
                x = *(const float4*)(eout + base);
            }
            const float4 ev = *(const float4*)(e + base);
            float4 v;
            v.x = fmaf(x.x, sc.x, sh.x) + ev.x;
            v.y = fmaf(x.y, sc.y, sh.y) + ev.y;
            v.z = fmaf(x.z, sc.z, sh.z) + ev.z;
            v.w = fmaf(x.w, sc.w, sh.w) + ev.w;
            *(float4*)(eout + base) = v;
            acc.x += v.x; acc.y += v.y; acc.z += v.z; acc.w += v.w;
        }
    }

    acc.x += __shfl_xor(acc.x, 32);
    acc.y += __shfl_xor(acc.y, 32);
    acc.z += __shfl_xor(acc.z, 32);
    acc.w += __shfl_xor(acc.w, 32);
    if (half == 0)
        *(float4*)(agg + (size_t)node * D + c0) = acc;
}

// h_new = y2*scale + shift + h (in-place over y2 in d_out)
__global__ __launch_bounds__(256) void node_apply_kernel(
    const float* __restrict__ h, const float* __restrict__ stats,
    float* __restrict__ hout)
{
    const int gid = blockIdx.x * 256 + threadIdx.x;
    const int c0  = (gid & 31) * 4;
    const size_t base = (size_t)(gid >> 5) * D + c0;

    const float4 sc = *(const float4*)(stats + 256 + c0);
    const float4 sh = *(const float4*)(stats + 384 + c0);
    const float4 x  = *(const float4*)(hout + base);
    const float4 hv = *(const float4*)(h + base);
    float4 v;
    v.x = fmaf(x.x, sc.x, sh.x) + hv.x;
    v.y = fmaf(x.y, sc.y, sh.y) + hv.y;
    v.z = fmaf(x.z, sc.z, sh.z) + hv.z;
    v.w = fmaf(x.w, sc.w, sh.w) + hv.w;
    *(float4*)(hout + base) = v;
}

extern "C" void kernel_launch(void* const* d_in, const int* in_sizes, int n_in,
                              void* d_out, int out_size, void* d_ws, size_t ws_size,
                              hipStream_t stream)
{
    const float* h   = (const float*)d_in[0];
    const float* e   = (const float*)d_in[1];
    const int*   src = (const int*)d_in[2];
    const int*   dst = (const int*)d_in[3];
    const float* Wa1 = (const float*)d_in[4];
    const float* ba1 = (const float*)d_in[5];
    const float* Wa2 = (const float*)d_in[6];
    const float* ba2 = (const float*)d_in[7];
    const float* Wb1 = (const float*)d_in[8];
    const float* bb1 = (const float*)d_in[9];
    const float* Wb2 = (const float*)d_in[10];
    const float* bb2 = (const float*)d_in[11];
    const float* ga  = (const float*)d_in[12];
    const float* bea = (const float*)d_in[13];
    const float* gb  = (const float*)d_in[14];
    const float* beb = (const float*)d_in[15];

    float* out  = (float*)d_out;
    float* hnew = out;                      // NN*D (y2 scratch, then h_new)
    float* enew = out + (size_t)NN * D;     // NE*D (e_new; x2 scratch if f32 path)

    // ws layout (float units):
    //   estats[512] | nstats[512] | icnt[NN] | ioff[NN+1] | pad3 |
    //   wtb1/wtb2/wta1/wta2 (4 x 16384 ushort) | csr[NE ints] | agg[NN*D] |
    //   x2h[NE*D halves]  (only if ws_size permits)
    float* ws     = (float*)d_ws;
    float* estats = ws;
    float* nstats = ws + 512;
    int*   icnt   = (int*)(ws + 1024);
    int*   ioff   = icnt + NN;
    unsigned short* wtb1 = (unsigned short*)(ioff + NN + 1 + 3);  // 16B aligned
    unsigned short* wtb2 = wtb1 + 16384;
    unsigned short* wta1 = wtb2 + 16384;
    unsigned short* wta2 = wta1 + 16384;
    int*    icsr = (int*)(wta2 + 16384);
    float*  agg  = (float*)(icsr + NE);
    __half* x2h  = (__half*)(agg + (size_t)NN * D);
    const size_t need_half = (size_t)((char*)(x2h + (size_t)NE * D) - (char*)d_ws);
    const bool use_half = (ws_size >= need_half);

    // zero BN stats + histogram counters
    hipMemsetAsync(d_ws, 0, (size_t)(1024 + NN) * sizeof(float), stream);

    // ---- weight prep (fragment-linear bf16) ----
    wprep_kernel<<<64, 256, 0, stream>>>(Wb1, wtb1);
    wprep_kernel<<<64, 256, 0, stream>>>(Wb2, wtb2);
    wprep_kernel<<<64, 256, 0, stream>>>(Wa1, wta1);
    wprep_kernel<<<64, 256, 0, stream>>>(Wa2, wta2);

    // ---- CSR build ----
    hist_kernel<<<(NE + 255) / 256, 256, 0, stream>>>(dst, icnt);
    scan_kernel<<<1, 1024, 0, stream>>>(icnt, ioff);
    csr_scatter_kernel<<<(NE + 255) / 256, 256, 0, stream>>>(dst, ioff, icnt, icsr);

    // ---- bond (edge) path ----
    if (use_half) {
        mlp_mfma_kernel<0, 1><<<NE / 64, 512, 0, stream>>>(
            h, e, src, dst, wtb1, bb1, wtb2, bb2, (void*)x2h, estats);
        bn_finalize_kernel<<<1, 128, 0, stream>>>(estats, gb, beb, 1.0f / NE);
        apply_gather_kernel<1><<<(NN + 3) / 4, 256, 0, stream>>>(
            e, estats, ioff, icsr, (const void*)x2h, enew, agg);
    } else {
        mlp_mfma_kernel<0, 0><<<NE / 64, 512, 0, stream>>>(
            h, e, src, dst, wtb1, bb1, wtb2, bb2, (void*)enew, estats);
        bn_finalize_kernel<<<1, 128, 0, stream>>>(estats, gb, beb, 1.0f / NE);
        apply_gather_kernel<0><<<(NN + 3) / 4, 256, 0, stream>>>(
            e, estats, ioff, icsr, nullptr, enew, agg);
    }

    // ---- atom (node) path ----
    mlp_mfma_kernel<1, 0><<<(NN + 63) / 64, 512, 0, stream>>>(
        h, agg, nullptr, nullptr, wta1, ba1, wta2, ba2, (void*)hnew, nstats);
    bn_finalize_kernel<<<1, 128, 0, stream>>>(nstats, ga, bea, 1.0f / NN);
    node_apply_kernel<<<(NN * 32) / 256, 256, 0, stream>>>(h, nstats, hnew);
}